// Round 6
// baseline (159.008 us; speedup 1.0000x reference)
//
#include <hip/hip_runtime.h>

#define LSEQ 384
#define NROWS 1536      // B*L
#define FDIM 640
#define HDIM 128
#define PART 196608     // 1536*128

// ws layout (float indices) — FIP/FJP partials consumed directly by k2 now
#define WS_FIP (4*PART)          // 4 x PART
#define WS_FJP (8*PART)          // 4 x PART
#define WS_QC  (14*PART)
#define WS_FLAG (WS_QC + NROWS)  // int[1536]

// out layout (float indices)
#define OUT_PC    0
#define OUT_TC    4608
#define OUT_NET   9216
#define OUT_POT   10752
#define OUT_MASK  12288
#define OUT_EN    602112

typedef float f4 __attribute__((ext_vector_type(4)));

__device__ __forceinline__ void gl16(const float* g, float* l) {
    __builtin_amdgcn_global_load_lds((const __attribute__((address_space(1))) float*)g,
                                     (__attribute__((address_space(3))) float*)l, 16, 0, 0);
}

// ===================== Kernel A: GEMM + H1 in-block epilogue =====================
// grid (48, 10), 256 threads:
//  by 0..1  : H1 blocks. BM=16 (96 blocks). Two 2-wave K-groups, each 10 tiles of
//             BK=32 over half of K (g*320..+320) into private LDS buffers; combine
//             through LDS; round-4-proven epilogue (bias/relu/BN/W2/W3/softmax)
//             writes PC/TC/NET + qc/flags. No H1 partials, no k_row.
//  by 2..9  : fi/fj split-K=4 (round-3/5 proven code): mat=1+((by-2)>>2), kz=(by-2)&3.
//             Writes partials to WS_FIP/WS_FJP; k2 sums the 4 partials inline.
__global__ __launch_bounds__(256) void kA(const float* __restrict__ X,
                                          const float* __restrict__ W1,
                                          const float* __restrict__ sW1,
                                          const float* __restrict__ b1,
                                          const float* __restrict__ gam,
                                          const float* __restrict__ bet,
                                          const float* __restrict__ rmean,
                                          const float* __restrict__ rvar,
                                          const float* __restrict__ W2,
                                          const float* __restrict__ b2,
                                          const float* __restrict__ W3,
                                          const float* __restrict__ b3,
                                          const int* __restrict__ seq,
                                          float* __restrict__ ws,
                                          float* __restrict__ out) {
    __shared__ __align__(16) float lds[18944];   // 74 KB union

    const int t  = threadIdx.x;
    const int bx = blockIdx.x;
    const int by = blockIdx.y;
    const int lane = t & 63;

    if (by == 0 && bx == 0 && t < 4) out[OUT_EN + t] = 0.0f;

    if (by >= 2) {
        // ---------------- fi/fj split-K=4 path (proven) ----------------
        const int by2 = by - 2;
        const int mat = by2 >> 2;            // 0=fi, 1=fj
        const int kz  = by2 & 3;
        const int m0  = bx * 32;
        const float* W = sW1 + mat * FDIM * HDIM;
        float* O = ws + (mat == 0 ? WS_FIP : WS_FJP) + kz * PART;
        const int k0 = kz * 160;             // 5 tiles of BK=32

        float* As = lds;                     // [2][32][36]: buf*1152 + k*36 + m
        float* Bs = lds + 2304;              // [2][32][128]: buf*4096 + k*128 + n

        const int wv = t >> 6;
        const int rg = t >> 5, cg = t & 31;
        const int ar = t >> 3, ac4 = (t & 7) * 4;

        auto stage_B = [&](int buf, int kk) {
            const float* src = W + (long)kk * HDIM;
            float* dst = Bs + buf * 4096;
#pragma unroll
            for (int i = 0; i < 4; i++) {
                const int c = wv * 4 + i;            // wave-uniform chunk
                gl16(src + c * 256 + lane * 4, dst + c * 256);
            }
        };

        f4 acc[4];
        acc[0] = acc[1] = acc[2] = acc[3] = (f4){0.f, 0.f, 0.f, 0.f};

        stage_B(0, k0);
        {
            f4 av = *(const f4*)&X[(long)(m0 + ar) * FDIM + k0 + ac4];
            As[(ac4 + 0) * 36 + ar] = av[0];
            As[(ac4 + 1) * 36 + ar] = av[1];
            As[(ac4 + 2) * 36 + ar] = av[2];
            As[(ac4 + 3) * 36 + ar] = av[3];
        }
        __syncthreads();

        for (int kt = 0; kt < 5; kt++) {
            const int buf = kt & 1;
            f4 av;
            if (kt < 4) {
                const int kk = k0 + (kt + 1) * 32;
                stage_B(buf ^ 1, kk);
                av = *(const f4*)&X[(long)(m0 + ar) * FDIM + kk + ac4];
            }
            const float* Ab = As + buf * 1152;
            const float* Bb = Bs + buf * 4096;
#pragma unroll
            for (int k = 0; k < 32; k++) {
                f4 a = *(const f4*)&Ab[k * 36 + rg * 4];
                f4 b = *(const f4*)&Bb[k * 128 + cg * 4];
                acc[0] += a[0] * b;
                acc[1] += a[1] * b;
                acc[2] += a[2] * b;
                acc[3] += a[3] * b;
            }
            if (kt < 4) {
                float* Aw = As + (buf ^ 1) * 1152;
                Aw[(ac4 + 0) * 36 + ar] = av[0];
                Aw[(ac4 + 1) * 36 + ar] = av[1];
                Aw[(ac4 + 2) * 36 + ar] = av[2];
                Aw[(ac4 + 3) * 36 + ar] = av[3];
            }
            __syncthreads();
        }

#pragma unroll
        for (int r = 0; r < 4; r++)
            *(f4*)&O[(long)(m0 + rg * 4 + r) * HDIM + cg * 4] = acc[r];
        return;
    }

    // ---------------- H1 path: BM=16, two 2-wave K-groups ----------------
    const int hb = by * 48 + bx;             // 0..95
    const int m0 = hb * 16;
    const int g  = t >> 7;                   // K-group 0/1
    const int tg = t & 127;                  // id in group
    const int wvg = tg >> 6;                 // wave in group (0/1)
    const int rg = tg >> 5;                  // 0..3 (4 rows each)
    const int cg = tg & 31;                  // 0..31 (4 cols each)
    const int ar = tg >> 3, ac4 = (tg & 7) * 4;   // A stage: 16 rows x 8 col4s
    const int k0g = g * 320;                 // half of K per group, 10 tiles

    float* As = lds + g * 9472;              // [2][32][20]: buf*640 + k*20 + m
    float* Bs = lds + g * 9472 + 1280;       // [2][32][128]: buf*4096 + k*128 + n

    auto stage_Bh = [&](int buf, int kk) {
        const float* src = W1 + (long)kk * HDIM;
        float* dst = Bs + buf * 4096;
#pragma unroll
        for (int i = 0; i < 8; i++) {
            const int c = wvg * 8 + i;               // wave-uniform chunk
            gl16(src + c * 256 + lane * 4, dst + c * 256);
        }
    };

    f4 acc[4];
    acc[0] = acc[1] = acc[2] = acc[3] = (f4){0.f, 0.f, 0.f, 0.f};

    stage_Bh(0, k0g);
    {
        f4 av = *(const f4*)&X[(long)(m0 + ar) * FDIM + k0g + ac4];
        As[(ac4 + 0) * 20 + ar] = av[0];
        As[(ac4 + 1) * 20 + ar] = av[1];
        As[(ac4 + 2) * 20 + ar] = av[2];
        As[(ac4 + 3) * 20 + ar] = av[3];
    }
    __syncthreads();

    for (int kt = 0; kt < 10; kt++) {
        const int buf = kt & 1;
        f4 av;
        if (kt < 9) {
            const int kk = k0g + (kt + 1) * 32;
            stage_Bh(buf ^ 1, kk);
            av = *(const f4*)&X[(long)(m0 + ar) * FDIM + kk + ac4];
        }
        const float* Ab = As + buf * 640;
        const float* Bb = Bs + buf * 4096;
#pragma unroll
        for (int k = 0; k < 32; k++) {
            f4 a = *(const f4*)&Ab[k * 20 + rg * 4];
            f4 b = *(const f4*)&Bb[k * 128 + cg * 4];
            acc[0] += a[0] * b;
            acc[1] += a[1] * b;
            acc[2] += a[2] * b;
            acc[3] += a[3] * b;
        }
        if (kt < 9) {
            float* Aw = As + (buf ^ 1) * 640;
            Aw[(ac4 + 0) * 20 + ar] = av[0];
            Aw[(ac4 + 1) * 20 + ar] = av[1];
            Aw[(ac4 + 2) * 20 + ar] = av[2];
            Aw[(ac4 + 3) * 20 + ar] = av[3];
        }
        __syncthreads();
    }

    // combine the two K-halves through LDS: hs[g][16][128]
    float* hs = lds;                          // reuse (all compute done, barrier above)
#pragma unroll
    for (int r = 0; r < 4; r++)
        *(f4*)&hs[g * 2048 + (rg * 4 + r) * 128 + cg * 4] = acc[r];
    __syncthreads();

    if (t >= 128) return;                     // epilogue on waves 0-1 (8 rows each)
    const int wv01 = t >> 6;

    float h0[8], h1[8];
#pragma unroll
    for (int rr = 0; rr < 8; rr++) {
        const int rl = wv01 * 8 + rr;        // local row 0..15
        float a0 = hs[rl * 128 + lane]      + hs[2048 + rl * 128 + lane];
        float a1 = hs[rl * 128 + 64 + lane] + hs[2048 + rl * 128 + 64 + lane];
        a0 = fmaxf(a0 + b1[lane], 0.0f);
        a1 = fmaxf(a1 + b1[64 + lane], 0.0f);
        h0[rr] = gam[lane]      * (a0 - rmean[lane])      / sqrtf(rvar[lane] + 1e-5f)      + bet[lane];
        h1[rr] = gam[64 + lane] * (a1 - rmean[64 + lane]) / sqrtf(rvar[64 + lane] + 1e-5f) + bet[64 + lane];
    }

    const float b2v = b2[lane];
    float a2[8];
#pragma unroll
    for (int rr = 0; rr < 8; rr++) a2[rr] = b2v;
#pragma unroll 4
    for (int cc = 0; cc < 64; cc++) {
        const float wv0 = W2[cc * 64 + lane];
        const float wv1 = W2[(cc + 64) * 64 + lane];
#pragma unroll
        for (int rr = 0; rr < 8; rr++) {
            float hv0 = __uint_as_float(__builtin_amdgcn_readlane(__float_as_uint(h0[rr]), cc));
            float hv1 = __uint_as_float(__builtin_amdgcn_readlane(__float_as_uint(h1[rr]), cc));
            a2[rr] = fmaf(hv0, wv0, a2[rr]);
            a2[rr] = fmaf(hv1, wv1, a2[rr]);
        }
    }

    const float w30 = W3[lane * 3 + 0], w31 = W3[lane * 3 + 1], w32 = W3[lane * 3 + 2];
#pragma unroll
    for (int rr = 0; rr < 8; rr++) {
        float h2 = fmaxf(a2[rr], 0.0f);
        float x0 = h2 * w30, x1 = h2 * w31, x2 = h2 * w32;
#pragma unroll
        for (int o = 32; o > 0; o >>= 1) {
            x0 += __shfl_xor(x0, o, 64);
            x1 += __shfl_xor(x1, o, 64);
            x2 += __shfl_xor(x2, o, 64);
        }
        if (lane == 0) {
            const int row = m0 + wv01 * 8 + rr;
            float l0 = x0 + b3[0], l1 = x1 + b3[1], l2 = x2 + b3[2];
            float m = fmaxf(l0, fmaxf(l1, l2));
            float e0 = expf(l0 - m), e1 = expf(l1 - m), e2 = expf(l2 - m);
            float s = e0 + e1 + e2;
            float pc0 = e0 / s, pc1 = e1 / s, pc2 = e2 / s;
            out[OUT_PC + row * 3 + 0] = pc0;
            out[OUT_PC + row * 3 + 1] = pc1;
            out[OUT_PC + row * 3 + 2] = pc2;
            float net = pc0 - pc1;
            out[OUT_NET + row] = net;
            ws[WS_QC + row] = net;
            ((int*)(ws + WS_FLAG))[row] = (pc0 > pc2 ? 1 : 0) | (pc1 > pc2 ? 2 : 0);
            int sid = seq[row];
            float c0 = (sid == 6 || sid == 8 || sid == 14) ? 1.0f : 0.0f;
            float c1 = (sid == 2 || sid == 3) ? 1.0f : 0.0f;
            out[OUT_TC + row * 3 + 0] = c0;
            out[OUT_TC + row * 3 + 1] = c1;
            out[OUT_TC + row * 3 + 2] = (c0 == 0.0f && c1 == 0.0f) ? 1.0f : 0.0f;
        }
    }
}

// =========== Kernel 2: conv + pair sweep (4 rows/block) + candidate MLP ===========
// mlp_eval sums the 4 split-K partials of fi/fj inline (candidates are rare).
__device__ __forceinline__ float mlp_eval(const float* __restrict__ fip, const float* __restrict__ fjp,
                                          int gi, int gj, float D,
                                          float dv0, float dv1, float sb0, float sb1v,
                                          float b2v, float w3l, const float* w2s, int lane) {
    const long bi0 = (long)gi * 128 + lane;
    const long bj0 = (long)gj * 128 + lane;
    float fi0 = ((fip[bi0] + fip[PART + bi0]) + fip[2 * PART + bi0]) + fip[3 * PART + bi0];
    float fi1 = ((fip[bi0 + 64] + fip[PART + bi0 + 64]) + fip[2 * PART + bi0 + 64]) + fip[3 * PART + bi0 + 64];
    float fj0 = ((fjp[bj0] + fjp[PART + bj0]) + fjp[2 * PART + bj0]) + fjp[3 * PART + bj0];
    float fj1 = ((fjp[bj0 + 64] + fjp[PART + bj0 + 64]) + fjp[2 * PART + bj0 + 64]) + fjp[3 * PART + bj0 + 64];
    float h0 = fmaxf(fi0 + fj0 + D * dv0 + sb0, 0.0f);
    float h1 = fmaxf(fi1 + fj1 + D * dv1 + sb1v, 0.0f);
    float a0 = 0.0f, a1 = 0.0f;
#pragma unroll
    for (int cc = 0; cc < 64; cc++) {
        float hv0 = __uint_as_float(__builtin_amdgcn_readlane(__float_as_uint(h0), cc));
        float hv1 = __uint_as_float(__builtin_amdgcn_readlane(__float_as_uint(h1), cc));
        a0 = fmaf(hv0, w2s[cc * 64 + lane], a0);
        a1 = fmaf(hv1, w2s[(cc + 64) * 64 + lane], a1);
    }
    float x = fmaxf(a0 + a1 + b2v, 0.0f) * w3l;
#pragma unroll
    for (int o = 32; o > 0; o >>= 1) x += __shfl_xor(x, o, 64);
    return x;
}

__global__ __launch_bounds__(256) void k2(const float* __restrict__ S,
                                          const float* __restrict__ ws,
                                          const float* __restrict__ sW1,
                                          const float* __restrict__ sb1,
                                          const float* __restrict__ sW2,
                                          const float* __restrict__ sb2,
                                          const float* __restrict__ sW3,
                                          const float* __restrict__ sb3,
                                          const float* __restrict__ c1w, const float* __restrict__ c1b,
                                          const float* __restrict__ c2w, const float* __restrict__ c2b,
                                          const float* __restrict__ c3w, const float* __restrict__ c3b,
                                          float* __restrict__ out) {
    __shared__ char smem[40960];
    const int t = threadIdx.x;
    const int bi = blockIdx.x;

    if (bi < 4) {
        float* p0 = (float*)smem;
        float* p1 = p0 + 388;
        float* p2 = p1 + 16 * 386;
        const int b = bi;
        for (int j = t; j < LSEQ; j += 256) p0[j + 2] = out[OUT_NET + b * LSEQ + j];
        if (t < 2) { p0[t] = 0.0f; p0[LSEQ + 2 + t] = 0.0f; }
        if (t < 16) { p1[t * 386] = 0.0f; p1[t * 386 + 385] = 0.0f; }
        if (t < 8)  { p2[t * 386] = 0.0f; p2[t * 386 + 385] = 0.0f; }
        __syncthreads();
        for (int pos = t; pos < LSEQ; pos += 256) {
#pragma unroll
            for (int o = 0; o < 16; o++) {
                float acc = c1b[o];
#pragma unroll
                for (int k = 0; k < 5; k++) acc = fmaf(p0[pos + k], c1w[o * 5 + k], acc);
                p1[o * 386 + pos + 1] = fmaxf(acc, 0.0f);
            }
        }
        __syncthreads();
        for (int pos = t; pos < LSEQ; pos += 256) {
#pragma unroll
            for (int o = 0; o < 8; o++) {
                float acc = c2b[o];
                for (int i = 0; i < 16; i++)
#pragma unroll
                    for (int k = 0; k < 3; k++)
                        acc = fmaf(p1[i * 386 + pos + k], c2w[(o * 16 + i) * 3 + k], acc);
                p2[o * 386 + pos + 1] = fmaxf(acc, 0.0f);
            }
        }
        __syncthreads();
        for (int pos = t; pos < LSEQ; pos += 256) {
            float acc = c3b[0];
            for (int i = 0; i < 8; i++)
#pragma unroll
                for (int k = 0; k < 3; k++)
                    acc = fmaf(p2[i * 386 + pos + k], c3w[i * 3 + k], acc);
            out[OUT_POT + b * LSEQ + pos] = acc;
        }
        return;
    }

    float* sx = (float*)smem;                         // 384
    float* sy = sx + 384;
    float* sz = sy + 384;
    float* sq = sz + 384;                             // @1152
    unsigned int* clist = (unsigned int*)(sx + 1536); // 384 entries, bytes 6144..7680
    unsigned char* sf = (unsigned char*)(smem + 7680);
    float* red = (float*)(smem + 8064);
    int* cntL = (int*)(smem + 8080);
    int* w2flag = (int*)(smem + 8084);
    float* w2s = (float*)(smem + 8192);               // 32KB

    const float* qc = ws + WS_QC;
    const int* flags = (const int*)(ws + WS_FLAG);
    const float* fip = ws + WS_FIP;
    const float* fjp = ws + WS_FJP;

    const int rowblk = bi - 4;            // 0..383
    const int b = rowblk / 96;
    const int i0 = (rowblk % 96) * 4;

    for (int j = t; j < LSEQ; j += 256) {
        int g = b * LSEQ + j;
        sx[j] = S[g * 3 + 0];
        sy[j] = S[g * 3 + 1];
        sz[j] = S[g * 3 + 2];
        sq[j] = qc[g];
        sf[j] = (unsigned char)flags[g];
    }
    if (t == 0) *w2flag = 0;
    __syncthreads();

    const int lane = t & 63, w = t >> 6;
    const float* dvec = sW1 + 1280 * 128;
    const float dv0 = dvec[lane], dv1 = dvec[lane + 64];
    const float sb0 = sb1[lane], sb1v = sb1[lane + 64];
    const float w3l = sW3[lane];
    const float b2v = sb2[lane];
    const float b3v = sb3[0];

    float esum = 0.0f;     // accumulated across all 4 rows, reduced once at end

    for (int r = 0; r < 4; r++) {
        const int i = i0 + r;
        const int grow = b * LSEQ + i;
        if (t == 0) *cntL = 0;
        __syncthreads();

        const float six = sx[i], siy = sy[i], siz = sz[i], qi = sq[i];
        const int fli = sf[i];
        const bool posi = (fli & 1) != 0, negi = (fli & 2) != 0;
        float* mrow = out + OUT_MASK + (long)grow * LSEQ;

        for (int j = t; j < LSEQ; j += 256) {
            float dx = __fsub_rn(six, sx[j]);
            float dy = __fsub_rn(siy, sy[j]);
            float dz = __fsub_rn(siz, sz[j]);
            float d2 = __fadd_rn(__fadd_rn(__fmul_rn(dx, dx), __fmul_rn(dy, dy)), __fmul_rn(dz, dz));
            d2 = __fadd_rn(d2, 1e-12f);
            float D = __fsqrt_rn(d2);
            mrow[j] = 0.0f;
            if (j > i && D < 15.0f && D > 0.0f) {
                float num = __fmul_rn(__fmul_rn(332.0f, qi), sq[j]);
                float den = __fmul_rn(__fmul_rn(20.0f, D), D);
                esum += __fdiv_rn(num, den);
            }
            int flj = sf[j];
            bool near = (D < 4.0f);
            bool need1 = near && posi && ((flj & 2) != 0);
            bool need2 = near && negi && ((flj & 1) != 0);
            if (need1 || need2) {
                int p = atomicAdd(cntL, 1);
                clist[p] = (unsigned int)j | (need1 ? 512u : 0u) | (need2 ? 1024u : 0u);
            }
        }
        __syncthreads();                  // clist complete

        int nc = *cntL;                   // uniform
        if (nc > 0) {
            if (!*w2flag) {               // lazy one-time w2s stage (uniform branch)
                for (int idx = t; idx < 2048; idx += 256)
                    ((float4*)w2s)[idx] = ((const float4*)sW2)[idx];
                __syncthreads();
                if (t == 0) *w2flag = 1;
            }
            for (int c = w; c < nc; c += 4) {
                unsigned int e = clist[c];
                int j = (int)(e & 511u);
                bool need1 = (e & 512u) != 0, need2 = (e & 1024u) != 0;
                float dx = __fsub_rn(six, sx[j]);
                float dy = __fsub_rn(siy, sy[j]);
                float dz = __fsub_rn(siz, sz[j]);
                float d2 = __fadd_rn(__fadd_rn(__fmul_rn(dx, dx), __fmul_rn(dy, dy)), __fmul_rn(dz, dz));
                d2 = __fadd_rn(d2, 1e-12f);
                float D = __fsqrt_rn(d2);
                int gi = grow, gj = b * LSEQ + j;
                bool hit = false;
                if (need1) {
                    float x = mlp_eval(fip, fjp, gi, gj, D, dv0, dv1, sb0, sb1v, b2v, w3l, w2s, lane);
                    hit = (x + b3v) > 0.0f;
                }
                if (!hit && need2) {
                    float x = mlp_eval(fip, fjp, gj, gi, D, dv0, dv1, sb0, sb1v, b2v, w3l, w2s, lane);
                    hit = (x + b3v) > 0.0f;
                }
                if (hit && lane == 0) mrow[j] = 1.0f;
            }
        }
        __syncthreads();                  // clist/cnt reuse safety
    }

    // block-wide energy reduce, one atomicAdd per block
#pragma unroll
    for (int o = 32; o > 0; o >>= 1) esum += __shfl_xor(esum, o, 64);
    if (lane == 0) red[w] = esum;
    __syncthreads();
    if (t == 0) {
        float s = red[0] + red[1] + red[2] + red[3];
        atomicAdd(&out[OUT_EN + b], s);
    }
}

extern "C" void kernel_launch(void* const* d_in, const int* in_sizes, int n_in,
                              void* d_out, int out_size, void* d_ws, size_t ws_size,
                              hipStream_t stream) {
    const float* X     = (const float*)d_in[0];
    const int*   seq   = (const int*)d_in[1];
    const float* S     = (const float*)d_in[2];
    const float* W1    = (const float*)d_in[3];
    const float* b1    = (const float*)d_in[4];
    const float* gam   = (const float*)d_in[5];
    const float* bet   = (const float*)d_in[6];
    const float* rmean = (const float*)d_in[7];
    const float* rvar  = (const float*)d_in[8];
    const float* W2    = (const float*)d_in[9];
    const float* b2    = (const float*)d_in[10];
    const float* W3    = (const float*)d_in[11];
    const float* b3    = (const float*)d_in[12];
    const float* sW1   = (const float*)d_in[13];
    const float* sb1   = (const float*)d_in[14];
    const float* sW2   = (const float*)d_in[15];
    const float* sb2   = (const float*)d_in[16];
    const float* sW3   = (const float*)d_in[17];
    const float* sb3   = (const float*)d_in[18];
    const float* c1w   = (const float*)d_in[19];
    const float* c1b   = (const float*)d_in[20];
    const float* c2w   = (const float*)d_in[21];
    const float* c2b   = (const float*)d_in[22];
    const float* c3w   = (const float*)d_in[23];
    const float* c3b   = (const float*)d_in[24];

    float* out = (float*)d_out;
    float* ws  = (float*)d_ws;

    hipLaunchKernelGGL(kA, dim3(48, 10), dim3(256), 0, stream,
                       X, W1, sW1, b1, gam, bet, rmean, rvar, W2, b2, W3, b3, seq, ws, out);
    hipLaunchKernelGGL(k2, dim3(388), dim3(256), 0, stream,
                       S, ws, sW1, sb1, sW2, sb2, sW3, sb3,
                       c1w, c1b, c2w, c2b, c3w, c3b, out);
}